// Round 2
// 168.147 us; speedup vs baseline: 1.0055x; 1.0055x over previous
//
#include <hip/hip_runtime.h>

#define NN 100000
#define NE 1600000
#define HID 64
#define NBUK 391              // buckets of 256 node ids: (NN+255)/256
#define SRCBITS 17
#define SRCMASK 0x1FFFF
#define EBLK 4096             // edges per block
#define GE2 ((NE + EBLK - 1) / EBLK)        // 391 edge-blocks
#define BSTRIDE 6144          // fixed bbuf slots per bucket (mean 4096, 32 sigma headroom)

typedef __attribute__((ext_vector_type(8))) short bf16x8;
typedef __attribute__((ext_vector_type(4))) float f32x4;

__device__ __forceinline__ float bf2f(unsigned short u) {
    return __uint_as_float(((unsigned int)u) << 16);
}
__device__ __forceinline__ unsigned short f2bf(float f) {   // RTNE
    unsigned int x = __float_as_uint(f);
    return (unsigned short)((x + 0x7FFFu + ((x >> 16) & 1u)) >> 16);
}
__device__ __forceinline__ float bflo(unsigned int u) { return __uint_as_float(u << 16); }
__device__ __forceinline__ float bfhi(unsigned int u) { return __uint_as_float(u & 0xFFFF0000u); }

// ---- fused hist + place: stage 4096 edges in LDS, histogram, reserve ------
// per-bucket space via global atomics (fixed-stride regions => NO global
// scan), scatter packed edges. Last-arriving block (arrival counter, no
// spin) exclusive-scans bucket totals -> global csr bases.
__global__ void __launch_bounds__(256)
k_fill1(const int* __restrict__ ei, int* __restrict__ gcnt,
        int* __restrict__ arrival, int* __restrict__ bucketBase,
        unsigned int* __restrict__ bbuf) {
    __shared__ int s_src[EBLK];   // 16 KB
    __shared__ int s_dst[EBLK];   // 16 KB
    __shared__ int s_hist[NBUK];  // hist, then cur (absolute positions)
    __shared__ int s_tmp[256];
    __shared__ int s_flag;
    __shared__ int s_last;
    int t = threadIdx.x;  // 256
    int b = blockIdx.x;

    for (int i = t; i < NBUK; i += 256) s_hist[i] = 0;
    if (t < 64) {   // int64 edges have all-zero odd int32 words
        unsigned long long bal = __ballot(ei[2 * t + 1] != 0);
        if (t == 0) s_flag = (bal == 0ULL) ? 1 : 0;  // 1 => int64 layout
    }
    __syncthreads();
    int f = s_flag;
    int base = b * EBLK;
    int m = NE - base; if (m > EBLK) m = EBLK;

    if (f) {                               // int64: int4 = 2 edges' words
        const int4* ps = (const int4*)ei;
        const int4* pd = (const int4*)(ei + 2 * (size_t)NE);
#pragma unroll
        for (int k = 0; k < EBLK / 512; ++k) {
            int e = base + k * 512 + t * 2;
            if (e < NE) {                  // NE even, e even -> e+1 valid
                int4 vs = ps[e >> 1];
                int4 vd = pd[e >> 1];
                int l = e - base;
                s_src[l] = vs.x;     s_dst[l] = vd.x;
                s_src[l + 1] = vs.z; s_dst[l + 1] = vd.z;
                atomicAdd(&s_hist[vd.x >> 8], 1);
                atomicAdd(&s_hist[vd.z >> 8], 1);
            }
        }
    } else {                               // int32: int4 = 4 edges
        const int4* ps = (const int4*)ei;
        const int4* pd = (const int4*)(ei + NE);
#pragma unroll
        for (int k = 0; k < EBLK / 1024; ++k) {
            int e = base + k * 1024 + t * 4;
            if (e < NE) {                  // NE % 4 == 0 -> whole quad valid
                int4 vs = ps[e >> 2];
                int4 vd = pd[e >> 2];
                int l = e - base;
                s_src[l] = vs.x; s_src[l + 1] = vs.y; s_src[l + 2] = vs.z; s_src[l + 3] = vs.w;
                s_dst[l] = vd.x; s_dst[l + 1] = vd.y; s_dst[l + 2] = vd.z; s_dst[l + 3] = vd.w;
                atomicAdd(&s_hist[vd.x >> 8], 1);
                atomicAdd(&s_hist[vd.y >> 8], 1);
                atomicAdd(&s_hist[vd.z >> 8], 1);
                atomicAdd(&s_hist[vd.w >> 8], 1);
            }
        }
    }
    __syncthreads();
    // reserve per-bucket chunks; cur[i] = absolute bbuf position
    for (int i = t; i < NBUK; i += 256) {
        int c = s_hist[i];
        int r = atomicAdd(&gcnt[i], c);            // device-scope, L2-serialized
        s_hist[i] = i * BSTRIDE + r;
    }
    __syncthreads();
    // scatter staged edges
    for (int e = t; e < m; e += 256) {
        int d = s_dst[e];
        int p = atomicAdd(&s_hist[d >> 8], 1);
        bbuf[p] = ((unsigned int)(d & 255) << SRCBITS) | (unsigned int)s_src[e];
    }
    __syncthreads();
    if (t == 0) s_last = atomicAdd(arrival, 1);    // after ALL this block's work
    __syncthreads();
    if (s_last == GE2 - 1) {
        // last block: exclusive scan of gcnt[0..NBUK-1] -> bucketBase[0..NBUK]
        int i0 = 2 * t, i1 = 2 * t + 1;
        int v0 = (i0 < NBUK) ? atomicAdd(&gcnt[i0], 0) : 0;   // coherent read
        int v1 = (i1 < NBUK) ? atomicAdd(&gcnt[i1], 0) : 0;
        int ps2 = v0 + v1;
        s_tmp[t] = ps2; __syncthreads();
        for (int off = 1; off < 256; off <<= 1) {
            int u = (t >= off) ? s_tmp[t - off] : 0;
            __syncthreads();
            s_tmp[t] += u;
            __syncthreads();
        }
        int run = s_tmp[t] - ps2;
        if (i0 <= NBUK) bucketBase[i0] = run;
        if (i1 <= NBUK) bucketBase[i1] = run + v0;
    }
}

// ---- pass B: per-bucket 256-slot sort -> cnt/offs/dinv/xs + csr ------------
__global__ void k_passB(const unsigned int* __restrict__ bbuf, const int* __restrict__ gcnt,
                        const int* __restrict__ bucketBase, const float* __restrict__ x,
                        int* __restrict__ cnt, int* __restrict__ offs,
                        float* __restrict__ dinv, float* __restrict__ xs,
                        int* __restrict__ csr) {
    __shared__ int hist[256];
    __shared__ int scn[256];
    __shared__ int cur[256];
    int t = threadIdx.x;  // 256
    int b = blockIdx.x;
    int sz = gcnt[b];
    int csrbase = bucketBase[b];
    const unsigned int* buf = bbuf + (size_t)b * BSTRIDE;
    hist[t] = 0;
    __syncthreads();
    for (int e = t; e < sz; e += 256)
        atomicAdd(&hist[buf[e] >> SRCBITS], 1);
    __syncthreads();
    int deg = hist[t];
    scn[t] = deg; __syncthreads();
    for (int off = 1; off < 256; off <<= 1) {
        int u = (t >= off) ? scn[t - off] : 0;
        __syncthreads();
        scn[t] += u;
        __syncthreads();
    }
    int myoff = csrbase + scn[t] - deg;
    int node = b * 256 + t;
    if (node < NN) {
        cnt[node]  = deg;
        offs[node] = myoff;
        float d = 1.0f / sqrtf((float)(deg + 1));
        dinv[node] = d;
        float4 xv = ((const float4*)x)[node];
        float4 o; o.x = d * xv.x; o.y = d * xv.y; o.z = d * xv.z; o.w = d * xv.w;
        ((float4*)xs)[node] = o;
    }
    cur[t] = myoff;
    __syncthreads();
    for (int e = t; e < sz; e += 256) {
        unsigned int u = buf[e];
        int p = atomicAdd(&cur[u >> SRCBITS], 1);
        csr[p] = (int)(u & SRCMASK);
    }
}

// ---- fused: layer-1 aggregate (4 thr/node) + h1 + MFMA h1@W2 -> hs ---------
// 64 nodes/block, 256 threads. agg = dinv*(sum_nbr xs[s] + xs[self]).
// mfma_f32_16x16x32_bf16: A[m=lane&15][k=quad*8+j]; D col=lane&15, row=quad*4+reg.
__global__ void k_mm2(const float* __restrict__ xs, const int* __restrict__ cnt,
                      const int* __restrict__ offs, const int* __restrict__ csr,
                      const float* __restrict__ dinv,
                      const float* __restrict__ W1, const float* __restrict__ b1,
                      const float* __restrict__ W2, unsigned short* __restrict__ hs) {
    __shared__ unsigned short h1b[64 * 72];   // [localNode][k], bf16, pad 72
    __shared__ unsigned short w2t[64 * 72];   // [n][k], bf16 (W2 transposed)
    __shared__ float4 sPart[256];             // per-(part,node) partial sums
    __shared__ float4 sAgg[64];
    __shared__ float4 sXs[64];
    __shared__ float sW1[256];
    __shared__ float sb1[64];
    __shared__ float sdv[64];
    __shared__ int scnt[64];
    __shared__ int soff[64];
    int t = threadIdx.x;  // 256
    int base = blockIdx.x * 64;
    if (t < 64) {
        int g = base + t;
        bool ok = (g < NN);
        scnt[t] = ok ? cnt[g] : 0;
        soff[t] = ok ? offs[g] : 0;
        sdv[t]  = ok ? dinv[g] : 0.f;
        sXs[t]  = ok ? ((const float4*)xs)[g] : make_float4(0.f, 0.f, 0.f, 0.f);
        sb1[t]  = b1[t];
    }
    sW1[t] = W1[t];
    for (int i = t; i < 4096; i += 256) {     // W2 [k][n] fp32 -> w2t [n][k] bf16
        int k = i >> 6, n = i & 63;
        w2t[n * 72 + k] = f2bf(W2[i]);
    }
    if (blockIdx.x == 0 && t >= 128 && t < 192) hs[NN * 64 + (t - 128)] = 0;  // sentinel row
    __syncthreads();
    // aggregation: node_l = t&63, part = t>>6 handles j = part, part+4, ...
    {
        int node_l = t & 63, part = t >> 6;
        int n = scnt[node_l], b0 = soff[node_l];
        float4 s = make_float4(0.f, 0.f, 0.f, 0.f);
        int j = part;
        for (; j + 4 < n; j += 8) {           // 2 independent loads in flight
            int s0 = csr[b0 + j], s1 = csr[b0 + j + 4];
            float4 v0 = ((const float4*)xs)[s0];
            float4 v1 = ((const float4*)xs)[s1];
            s.x += v0.x + v1.x; s.y += v0.y + v1.y;
            s.z += v0.z + v1.z; s.w += v0.w + v1.w;
        }
        for (; j < n; j += 4) {
            int s0 = csr[b0 + j];
            float4 v = ((const float4*)xs)[s0];
            s.x += v.x; s.y += v.y; s.z += v.z; s.w += v.w;
        }
        sPart[t] = s;
    }
    __syncthreads();
    if (t < 64) {
        float4 a = sPart[t], b = sPart[t + 64], c = sPart[t + 128], d = sPart[t + 192];
        float4 xi = sXs[t];
        float dn = sdv[t];
        float4 o;
        o.x = dn * (a.x + b.x + c.x + d.x + xi.x);
        o.y = dn * (a.y + b.y + c.y + d.y + xi.y);
        o.z = dn * (a.z + b.z + c.z + d.z + xi.z);
        o.w = dn * (a.w + b.w + c.w + d.w + xi.w);
        sAgg[t] = o;
    }
    __syncthreads();
#pragma unroll
    for (int i = 0; i < 16; ++i) {            // h1 = relu(agg@W1+b1), bf16 to LDS
        int e = i * 256 + t;
        int nl = e >> 6, c = e & 63;
        float4 a = sAgg[nl];
        float h = fmaf(a.x, sW1[c], fmaf(a.y, sW1[64 + c],
                  fmaf(a.z, sW1[128 + c], fmaf(a.w, sW1[192 + c], sb1[c]))));
        h1b[nl * 72 + c] = f2bf(fmaxf(h, 0.f));
    }
    __syncthreads();
    int w = t >> 6, lane = t & 63, l15 = lane & 15, quad = lane >> 4;
    bf16x8 a0 = *(const bf16x8*)&h1b[(w * 16 + l15) * 72 + quad * 8];
    bf16x8 a1 = *(const bf16x8*)&h1b[(w * 16 + l15) * 72 + 32 + quad * 8];
    f32x4 acc[4];
#pragma unroll
    for (int nt = 0; nt < 4; ++nt) {
        bf16x8 bb0 = *(const bf16x8*)&w2t[(nt * 16 + l15) * 72 + quad * 8];
        bf16x8 bb1 = *(const bf16x8*)&w2t[(nt * 16 + l15) * 72 + 32 + quad * 8];
        f32x4 c = {0.f, 0.f, 0.f, 0.f};
        c = __builtin_amdgcn_mfma_f32_16x16x32_bf16(a0, bb0, c, 0, 0, 0);
        c = __builtin_amdgcn_mfma_f32_16x16x32_bf16(a1, bb1, c, 0, 0, 0);
        acc[nt] = c;
    }
#pragma unroll
    for (int nt = 0; nt < 4; ++nt) {
#pragma unroll
        for (int r = 0; r < 4; ++r) {
            int localn = w * 16 + quad * 4 + r;
            int g = base + localn;
            if (g < NN) hs[g * 64 + nt * 16 + l15] = f2bf(acc[nt][r] * sdv[localn]);
        }
    }
}

// ---- layer-2 gather + head, fused, quad-row loads (4 in flight). -----------
// Lane c: group qg=c>>4 takes edges j+qg (mod 4); slot ql=c&15 covers cols
// 4ql..4ql+3 (uint2 = 4 bf16). One wave-load = 4 neighbor rows.
__global__ void k_gather_head(const unsigned short* __restrict__ hs, const int* __restrict__ offs,
                              const int* __restrict__ cnt, const int* __restrict__ csr,
                              const float* __restrict__ dinv, const float* __restrict__ b2,
                              const float* __restrict__ Wl, const float* __restrict__ bl,
                              float* __restrict__ out) {
    int t = threadIdx.x;
    int node = blockIdx.x * 4 + (t >> 6);
    int c = t & 63;
    int qg = c >> 4;
    int ql = c & 15;
    int b = offs[node], n = cnt[node];
    const uint2* hrow = (const uint2*)hs;        // 16 uint2 per row
    int myidx = (c < n) ? csr[b + c] : NN;       // NN = zero sentinel row
    int m = n < 64 ? n : 64;
    float4 A = make_float4(0.f, 0.f, 0.f, 0.f);
    float4 B = make_float4(0.f, 0.f, 0.f, 0.f);
    for (int j = 0; j < m; j += 16) {            // 16 edges per iter, 4 loads in flight
        int s0 = __shfl(myidx, j + qg, 64);
        int s1 = __shfl(myidx, j + 4 + qg, 64);
        int s2 = __shfl(myidx, j + 8 + qg, 64);
        int s3 = __shfl(myidx, j + 12 + qg, 64);
        uint2 u0 = hrow[s0 * 16 + ql];
        uint2 u1 = hrow[s1 * 16 + ql];
        uint2 u2 = hrow[s2 * 16 + ql];
        uint2 u3 = hrow[s3 * 16 + ql];
        A.x += bflo(u0.x); A.y += bfhi(u0.x); A.z += bflo(u0.y); A.w += bfhi(u0.y);
        B.x += bflo(u1.x); B.y += bfhi(u1.x); B.z += bflo(u1.y); B.w += bfhi(u1.y);
        A.x += bflo(u2.x); A.y += bfhi(u2.x); A.z += bflo(u2.y); A.w += bfhi(u2.y);
        B.x += bflo(u3.x); B.y += bfhi(u3.x); B.z += bflo(u3.y); B.w += bfhi(u3.y);
    }
    for (int j = 64; j < n; j += 4) {            // rare: deg > 64
        int e = j + qg;
        int s = (e < n) ? csr[b + e] : NN;
        uint2 u = hrow[s * 16 + ql];
        A.x += bflo(u.x); A.y += bfhi(u.x); A.z += bflo(u.y); A.w += bfhi(u.y);
    }
    float4 S;
    S.x = A.x + B.x; S.y = A.y + B.y; S.z = A.z + B.z; S.w = A.w + B.w;
    S.x += __shfl_xor(S.x, 16, 64); S.x += __shfl_xor(S.x, 32, 64);
    S.y += __shfl_xor(S.y, 16, 64); S.y += __shfl_xor(S.y, 32, 64);
    S.z += __shfl_xor(S.z, 16, 64); S.z += __shfl_xor(S.z, 32, 64);
    S.w += __shfl_xor(S.w, 16, 64); S.w += __shfl_xor(S.w, 32, 64);
    uint2 uS = hrow[node * 16 + ql];             // self loop, once
    S.x += bflo(uS.x); S.y += bfhi(uS.x); S.z += bflo(uS.y); S.w += bfhi(uS.y);
    float4 bv = ((const float4*)b2)[ql];
    float4 wv = ((const float4*)Wl)[ql];
    float dn = dinv[node];
    float v = fmaxf(fmaf(dn, S.x, bv.x), 0.f) * wv.x
            + fmaxf(fmaf(dn, S.y, bv.y), 0.f) * wv.y
            + fmaxf(fmaf(dn, S.z, bv.z), 0.f) * wv.z
            + fmaxf(fmaf(dn, S.w, bv.w), 0.f) * wv.w;
#pragma unroll
    for (int off = 8; off; off >>= 1) v += __shfl_down(v, off, 16);
    if (c == 0) out[node] = v + bl[0];
}

extern "C" void kernel_launch(void* const* d_in, const int* in_sizes, int n_in,
                              void* d_out, int out_size, void* d_ws, size_t ws_size,
                              hipStream_t stream) {
    const float* x  = (const float*)d_in[0];
    const int*   ei = (const int*)d_in[1];
    const float* W1 = (const float*)d_in[2];
    const float* b1 = (const float*)d_in[3];
    const float* W2 = (const float*)d_in[4];
    const float* b2 = (const float*)d_in[5];
    const float* Wl = (const float*)d_in[6];
    const float* bl = (const float*)d_in[7];
    float* out = (float*)d_out;

    char* w = (char*)d_ws;
    float* dinv  = (float*)w;                  w += NN * 4;
    int*   cnt   = (int*)w;                    w += NN * 4;
    int*   offs  = (int*)w;                    w += NN * 4;
    int*   csr   = (int*)w;                    w += NE * 4;
    float* xs    = (float*)w;                  w += NN * 4 * 4;
    unsigned short* hs = (unsigned short*)w;   w += (size_t)(NN + 1) * HID * 2;     // 12.8 MB (+sentinel)
    int*   gcnt  = (int*)w;                    w += NBUK * 4;
    int*   arrival = (int*)w;                  w += 4;
    int*   bucketBase = (int*)w;               w += (NBUK + 1) * 4;
    w = (char*)(((size_t)w + 255) & ~(size_t)255);
    unsigned int* bbuf = (unsigned int*)w;     w += (size_t)NBUK * BSTRIDE * 4;     // 9.6 MB

    const int GMM = (NN + 63) / 64;        // 1563

    // zero gcnt + arrival (contiguous) each replay
    hipMemsetAsync(gcnt, 0, (NBUK + 1) * sizeof(int), stream);
    hipLaunchKernelGGL(k_fill1, dim3(GE2),  dim3(256), 0, stream,
                       ei, gcnt, arrival, bucketBase, bbuf);
    hipLaunchKernelGGL(k_passB, dim3(NBUK), dim3(256), 0, stream,
                       bbuf, gcnt, bucketBase, x, cnt, offs, dinv, xs, csr);
    hipLaunchKernelGGL(k_mm2, dim3(GMM), dim3(256), 0, stream,
                       xs, cnt, offs, csr, dinv, W1, b1, W2, hs);
    hipLaunchKernelGGL(k_gather_head, dim3(NN / 4), dim3(256), 0, stream,
                       hs, offs, cnt, csr, dinv, b2, Wl, bl, out);
}